// Round 1
// baseline (1837.457 us; speedup 1.0000x reference)
//
#include <hip/hip_runtime.h>
#include <stdint.h>

typedef __attribute__((ext_vector_type(8))) __bf16 bf16x8;
typedef __attribute__((ext_vector_type(16))) float f32x16;

constexpr int CIN = 256, COUT = 256, HH = 512, WW = 512;
constexpr int BC = 16;     // input channels per K-iteration
constexpr int CPAD = 20;   // LDS channel stride (40B -> bank stride 10 -> only 2-way conflicts, free)
constexpr int MT = 128;    // out-channels per workgroup
constexpr int TY = 4, TX = 32;  // pixel tile: 4 rows x 32 cols

__device__ __forceinline__ unsigned short f2bf(float f) {
    union { float f; unsigned int u; } v; v.f = f;
    return (unsigned short)((v.u + 0x7fffu + ((v.u >> 16) & 1u)) >> 16);  // RNE
}

__device__ __forceinline__ bf16x8 ldsfrag(const unsigned short* p) {
    // 8-byte-aligned LDS loads (base stride is 40B, +0/+16 for c0 in {0,8})
    union { unsigned long long u[2]; bf16x8 v; } r;
    r.u[0] = *reinterpret_cast<const unsigned long long*>(p);
    r.u[1] = *reinterpret_cast<const unsigned long long*>(p + 4);
    return r.v;
}

// ws layout: Wt[tap][k][c] bf16, [9][256][256]; transposed so per-lane 8 consecutive c.
__global__ void wt_transform(const float* __restrict__ w, unsigned short* __restrict__ wt) {
    int idx = blockIdx.x * 256 + threadIdx.x;   // [0, 9*65536)
    int tap = idx >> 16;
    int rem = idx & 65535;
    int k = rem >> 8, c = rem & 255;
    wt[idx] = f2bf(w[((k << 8) | c) * 9 + tap]);
}

__global__ __launch_bounds__(256, 3)
void conv_mfma(const float* __restrict__ x, const unsigned short* __restrict__ wt,
               float* __restrict__ out) {
    __shared__ unsigned short Wlds[9][MT][CPAD];          // 46080 B
    __shared__ unsigned short Xt[TY + 2][TX + 2][CPAD];   //  8160 B  (total 54240 -> 3 blocks/CU)

    const int bid = blockIdx.x;
    const int k0 = (bid & 1) * MT;          // pair M-blocks of same tile for L2/LLC input reuse
    const int tile = bid >> 1;
    const int x0 = (tile & 15) * TX;
    const int y0 = (tile >> 4) * TY;

    const int tid = threadIdx.x;
    const int lane = tid & 63;
    const int wave = tid >> 6;
    const int wm = wave & 1;                // m-half (64 out-channels)
    const int wn = wave >> 1;               // n-half (pixel-row pair)
    const int ln31 = lane & 31;
    const int lh8 = (lane >> 5) * 8;        // k-offset of this lane's frag

    f32x16 acc[2][2];
    #pragma unroll
    for (int i = 0; i < 2; ++i)
        #pragma unroll
        for (int j = 0; j < 2; ++j)
            #pragma unroll
            for (int r = 0; r < 16; ++r) acc[i][j][r] = 0.f;

    for (int cb = 0; cb < CIN / BC; ++cb) {
        const int c0 = cb * BC;

        // ---- stage weight block: Wlds[tap][k][0..15] from pre-transposed bf16 ws (L2-resident)
        for (int e = tid; e < 9 * MT; e += 256) {
            const int tap = e >> 7;
            const int k = e & (MT - 1);
            const unsigned long long* src = reinterpret_cast<const unsigned long long*>(
                wt + ((tap * COUT + (k0 + k)) * CIN + c0));
            unsigned long long* dst = reinterpret_cast<unsigned long long*>(&Wlds[tap][k][0]);
            dst[0] = src[0]; dst[1] = src[1]; dst[2] = src[2]; dst[3] = src[3];
        }

        // ---- stage input slab (fp32 -> bf16, transposed): Xt[rr][xi][c] = x[c0+c][y0-1+rr][x0-1+xi]
        {
            const int rowid = tid >> 5, lx = tid & 31;
            for (int p = rowid; p < 6 * BC; p += 8) {
                const int rr = p >> 4, c = p & 15;
                const int yy = y0 - 1 + rr;
                const bool rowok = ((unsigned)yy < (unsigned)HH);
                const float* xrow = x + (long long)(c0 + c) * (HH * WW) + (long long)yy * WW;
                const int gx = x0 - 1 + lx;
                float v0 = (rowok && (unsigned)gx < (unsigned)WW) ? xrow[gx] : 0.f;
                Xt[rr][lx][c] = f2bf(v0);
                if (lx < 2) {                      // 2-element x-halo tail
                    const int gx2 = x0 + 31 + lx;
                    float v1 = (rowok && gx2 < WW) ? xrow[gx2] : 0.f;
                    Xt[rr][32 + lx][c] = f2bf(v1);
                }
            }
        }
        __syncthreads();

        // ---- 9 taps x (2x2 MFMA outer product), K=16 per mfma
        #pragma unroll
        for (int rr = 0; rr < 3; ++rr) {
            #pragma unroll
            for (int s = 0; s < 3; ++s) {
                const int tap = rr * 3 + s;
                bf16x8 a0 = ldsfrag(&Wlds[tap][wm * 64 + 0 + ln31][lh8]);
                bf16x8 a1 = ldsfrag(&Wlds[tap][wm * 64 + 32 + ln31][lh8]);
                bf16x8 b0 = ldsfrag(&Xt[wn * 2 + 0 + rr][s + ln31][lh8]);
                bf16x8 b1 = ldsfrag(&Xt[wn * 2 + 1 + rr][s + ln31][lh8]);
                acc[0][0] = __builtin_amdgcn_mfma_f32_32x32x16_bf16(a0, b0, acc[0][0], 0, 0, 0);
                acc[0][1] = __builtin_amdgcn_mfma_f32_32x32x16_bf16(a0, b1, acc[0][1], 0, 0, 0);
                acc[1][0] = __builtin_amdgcn_mfma_f32_32x32x16_bf16(a1, b0, acc[1][0], 0, 0, 0);
                acc[1][1] = __builtin_amdgcn_mfma_f32_32x32x16_bf16(a1, b1, acc[1][1], 0, 0, 0);
            }
        }
        __syncthreads();
    }

    // ---- epilogue: C/D map col=lane&31, row=(reg&3)+8*(reg>>2)+4*(lane>>5)
    #pragma unroll
    for (int i = 0; i < 2; ++i) {
        const int mb = k0 + wm * 64 + i * 32 + (lane >> 5) * 4;
        #pragma unroll
        for (int j = 0; j < 2; ++j) {
            const long long py = y0 + wn * 2 + j;
            const long long px = x0 + ln31;
            #pragma unroll
            for (int r = 0; r < 16; ++r) {
                const int m = mb + (r & 3) + 8 * (r >> 2);
                out[((long long)m * HH + py) * WW + px] = acc[i][j][r];
            }
        }
    }
}

// Safety fallback if ws is too small for the transposed weights (slow but correct).
__global__ void conv_naive(const float* __restrict__ x, const float* __restrict__ w,
                           float* __restrict__ out) {
    const int k = blockIdx.x;
    const int y = blockIdx.y;
    const int xx = blockIdx.z * 256 + threadIdx.x;
    float a = 0.f;
    for (int c = 0; c < CIN; ++c) {
        const float* wp = w + ((k * CIN + c) * 9);
        const float* xp = x + (long long)c * HH * WW;
        #pragma unroll
        for (int r = 0; r < 3; ++r) {
            const int yy = y + r - 1;
            if ((unsigned)yy >= (unsigned)HH) continue;
            const float* row = xp + (long long)yy * WW;
            #pragma unroll
            for (int s = 0; s < 3; ++s) {
                const int gx = xx + s - 1;
                const float v = ((unsigned)gx < (unsigned)WW) ? row[gx] : 0.f;
                a += wp[r * 3 + s] * v;
            }
        }
    }
    out[((long long)k * HH + y) * WW + xx] = a;
}

extern "C" void kernel_launch(void* const* d_in, const int* in_sizes, int n_in,
                              void* d_out, int out_size, void* d_ws, size_t ws_size,
                              hipStream_t stream) {
    const float* x = (const float*)d_in[0];
    const float* w = (const float*)d_in[1];
    float* out = (float*)d_out;

    const size_t wt_bytes = (size_t)9 * 256 * 256 * sizeof(unsigned short);
    if (ws_size >= wt_bytes) {
        unsigned short* wt = (unsigned short*)d_ws;
        wt_transform<<<2304, 256, 0, stream>>>(w, wt);           // rebuild every call (ws re-poisoned)
        conv_mfma<<<4096, 256, 0, stream>>>(x, wt, out);
    } else {
        conv_naive<<<dim3(256, 512, 2), 256, 0, stream>>>(x, w, out);
    }
}